// Round 10
// baseline (1052.251 us; speedup 1.0000x reference)
//
#include <hip/hip_runtime.h>
#include <hip/hip_bf16.h>

// Problem constants
#define B_   8192
#define S_   1152
#define G_   576
#define F_   16
#define L_   24
#define NP_  576
#define KA   1856      // padded K of A / Wt (29 * 64)
#define NCOL 9216      // F*G
#define KV   1984      // KA + 128 (virtual K incl. loop-weight blocks)

typedef float f32x4 __attribute__((ext_vector_type(4)));
typedef short short8_t __attribute__((ext_vector_type(8)));

// ---- bf16 helpers (RNE) ----
__device__ __forceinline__ short f2bf(float v) {
  unsigned u = __float_as_uint(v);
  unsigned r = (u + 0x7fffu + ((u >> 16) & 1u)) >> 16;
  return (short)r;
}
__device__ __forceinline__ float bf2f(short s) {
  return __uint_as_float(((unsigned)(unsigned short)s) << 16);
}

__device__ __forceinline__ float log_cosh_f(float t) {
  float a = fabsf(t);
  return a + __logf(1.f + __expf(-2.f * a)) - 0.6931471805599453f;
}

__device__ __forceinline__ float wave_sum(float v) {
  #pragma unroll
  for (int d = 1; d < 64; d <<= 1) v += __shfl_xor(v, d, 64);
  return v;
}

__device__ __forceinline__ void load_lds16(const void* g, void* l) {
  __builtin_amdgcn_global_load_lds(
      (const __attribute__((address_space(1))) void*)g,
      (__attribute__((address_space(3))) void*)l, 16, 0, 0);
}

// ============================================================
// Kernel 1: build A (bf16 features) + bias -> out[b]
// ============================================================
__global__ __launch_bounds__(256) void build_a_kernel(
    const float* __restrict__ x, const float* __restrict__ vb,
    const float* __restrict__ cb0, const float* __restrict__ cb1,
    const float* __restrict__ cb2,
    const int* __restrict__ idx0, const int* __restrict__ idx1,
    const int* __restrict__ idx2,
    short* __restrict__ A, float* __restrict__ out) {
  int b = blockIdx.x, t = threadIdx.x;
  __shared__ float xs[S_];
  __shared__ float red[20];
  float se = 0.f, so = 0.f, s0 = 0.f, s1 = 0.f, s2 = 0.f;
  const float* xr = x + (size_t)b * S_;
  short* Ar = A + (size_t)b * KA;

  for (int i = t; i < S_; i += 256) {
    float v = xr[i];
    xs[i] = v;
    Ar[i] = f2bf(v);
    if (i & 1) so += v; else se += v;
  }
  __syncthreads();

  for (int c = t; c < NP_; c += 256) {
    const int* q = idx0 + c * 4;
    float p = xs[q[0]] * xs[q[1]] * xs[q[2]] * xs[q[3]];
    s0 += p;
    Ar[S_ + c] = f2bf(p);
  }
  if (t < L_) {
    const int* q = idx1 + t * L_;
    float p = 1.f;
    #pragma unroll
    for (int j = 0; j < L_; ++j) p *= xs[q[j]];
    s1 = p;
    short hi = f2bf(p);
    Ar[1728 + t] = hi;
    Ar[1752 + t] = f2bf(p - bf2f(hi));
  }
  if (t >= 32 && t < 32 + L_) {
    int l = t - 32;
    const int* q = idx2 + l * L_;
    float p = 1.f;
    #pragma unroll
    for (int j = 0; j < L_; ++j) p *= xs[q[j]];
    s2 = p;
    short hi = f2bf(p);
    Ar[1792 + l] = hi;
    Ar[1816 + l] = f2bf(p - bf2f(hi));
  }
  if (t >= 64 && t < 80) Ar[1776 + (t - 64)] = 0;
  if (t >= 80 && t < 96) Ar[1840 + (t - 80)] = 0;

  se = wave_sum(se); so = wave_sum(so);
  s0 = wave_sum(s0); s1 = wave_sum(s1); s2 = wave_sum(s2);
  int w = t >> 6;
  if ((t & 63) == 0) {
    red[w] = se; red[4 + w] = so; red[8 + w] = s0;
    red[12 + w] = s1; red[16 + w] = s2;
  }
  __syncthreads();
  if (t == 0) {
    float a  = red[0] + red[1] + red[2] + red[3];
    float bb = red[4] + red[5] + red[6] + red[7];
    float c0 = red[8] + red[9] + red[10] + red[11];
    float c1 = red[12] + red[13] + red[14] + red[15];
    float c2 = red[16] + red[17] + red[18] + red[19];
    out[b] = vb[0] * a + vb[1] * bb + cb0[0] * c0 + cb1[0] * c1 + cb2[0] * c2;
  }
}

// ============================================================
// Kernel 2: gather weights.
// ============================================================
__global__ __launch_bounds__(256) void build_w_kernel(
    const float* __restrict__ symm_kernel, const int* __restrict__ symmetries,
    const float* __restrict__ c0k, const int* __restrict__ c0s,
    const float* __restrict__ c1k, const int* __restrict__ c1s,
    const float* __restrict__ c2k, const int* __restrict__ c2s,
    const float* __restrict__ l0k, const float* __restrict__ l1k,
    short* __restrict__ Wt, short* __restrict__ Wlt) {
  const int CHUNKS = KV / 8;  // 248
  int t = blockIdx.x * 256 + threadIdx.x;
  int n = t / CHUNKS;
  if (n >= NCOL) return;
  int ch = t - n * CHUNKS;
  int g = n >> 4, f = n & 15;
  int k0 = ch * 8;
  short8_t pack;
  #pragma unroll
  for (int j = 0; j < 8; ++j) {
    int k = k0 + j;
    float val;
    if (k < 1152) {
      val = symm_kernel[f * S_ + symmetries[g * S_ + k]];
    } else if (k < 1728) {
      int c = k - 1152;
      val = c0k[f * NP_ + c0s[g * NP_ + c]];
    } else if (k < 1792) {
      int c = k - 1728;
      val = (c < 48) ? c1k[f * L_ + c1s[g * L_ + (c < 24 ? c : c - 24)]] : 0.f;
    } else if (k < 1856) {
      int c = k - 1792;
      val = (c < 48) ? c2k[f * L_ + c2s[g * L_ + (c < 24 ? c : c - 24)]] : 0.f;
    } else if (k < 1920) {
      int c = k - 1856;
      val = (c < 48) ? l0k[f * L_ + c1s[g * L_ + (c < 24 ? c : c - 24)]] : 0.f;
    } else {
      int c = k - 1920;
      val = (c < 48) ? l1k[f * L_ + c2s[g * L_ + (c < 24 ? c : c - 24)]] : 0.f;
    }
    pack[j] = f2bf(val);
  }
  if (k0 < KA) *(short8_t*)(Wt + (size_t)n * KA + k0) = pack;
  else         *(short8_t*)(Wlt + (size_t)n * 128 + (k0 - KA)) = pack;
}

// ============================================================
// Kernel 3: fused GEMM + log_cosh reduction.
// r9 post-mortem: latency wall at 1 block/CU confirmed (spilling
// 10-wave/CU kernel ~matched clean 1-block/CU kernels). Occupancy
// without spill is the lever.
// Allocator law (r2/r8/r9): launch_bounds(.,N>=2) -> 128-VGPR clamp;
// waves_per_eu(min) -> free clamp (84); BOUNDED waves_per_eu(2,2)
// -> exactly <=256 VGPR, no deeper clamp.
// This round: 256x256 tile, 512 thr / 8 waves (2M x 4N), BK=64.
//  - r7-verified counted-vmcnt 2-buf loop (numerics verified r8)
//  - waves_per_eu(2,2): 2 waves/SIMD, no spill (demand ~235)
//  - af split in 2 groups of 4 (-16 VGPR)
//  - T5 setprio around MFMA clusters (role diversity w/ 8 waves)
//  - staging traffic halves vs 128^2 (4.53 -> 2.26 GB)
//  - XCD map: XCD owns 4 m-tiles; 32 concurrent blocks = 4m x 8n
//  - XOR chunk swizzle (0 conflicts, r2-verified)
// ============================================================
__global__ __launch_bounds__(512)
__attribute__((amdgpu_waves_per_eu(2, 2)))
void gemm_fused(
    const short* __restrict__ A, const short* __restrict__ Wt,
    const short* __restrict__ Wlt,
    const float* __restrict__ hidden_bias, const float* __restrict__ l0hb,
    const float* __restrict__ l1hb, float* __restrict__ out) {
  __shared__ short Als[2][256 * 64];
  __shared__ short Bls[2][256 * 64];
  const int tid = threadIdx.x;
  const int w = tid >> 6, lane = tid & 63;
  const int wm = w >> 2, wn = w & 3;          // 2M x 4N waves
  const int lr = lane & 15, lg = lane >> 4;

  // XCD-aware tile mapping (bijective: 1152 = 8 * 144)
  const int bid = blockIdx.x;
  const int xcd = bid & 7;
  const int j   = bid >> 3;                   // 0..143
  const int mt  = (xcd << 2) | (j & 3);       // XCD owns 4 m-tiles
  const int nt  = j >> 2;                     // 0..35
  const int m0 = mt * 256, n0 = nt * 256;

  // staging geometry: chunk p = i*512 + tid -> row = i*64 + (tid>>3)
  const int srow = tid >> 3;
  const int scol = ((tid & 7) ^ (srow & 7)) * 16;  // pre-swizzled src byte off

  f32x4 acc[8][4];
  float rs[8][4];
  #pragma unroll
  for (int i = 0; i < 8; ++i)
    #pragma unroll
    for (int jj = 0; jj < 4; ++jj) {
      #pragma unroll
      for (int q = 0; q < 4; ++q) acc[i][jj][q] = 0.f;
      rs[i][jj] = 0.f;
    }

  const char* Abase = (const char*)A + (size_t)m0 * (KA * 2);
  const char* Wbase = (const char*)Wt + (size_t)n0 * (KA * 2);
  const char* Lbase = (const char*)Wlt + (size_t)n0 * 256;

  // per-thread staging pointers, advanced +128 B per K-tile
  const char* pA[4];
  const char* pB[4];
  #pragma unroll
  for (int i = 0; i < 4; ++i) {
    pA[i] = Abase + (size_t)(i * 64 + srow) * (KA * 2) + scol;
    pB[i] = Wbase + (size_t)(i * 64 + srow) * (KA * 2) + scol;
  }

  auto stage_main = [&](int buf) {
    #pragma unroll
    for (int i = 0; i < 4; ++i) {
      load_lds16(pA[i], (char*)&Als[buf][0] + (i * 512 + tid) * 16);
      load_lds16(pB[i], (char*)&Bls[buf][0] + (i * 512 + tid) * 16);
      pA[i] += 128;
      pB[i] += 128;
    }
  };

  // loop-pass staging: A cols at aOff, Wlt rows (stride 256 B) at bOff
  auto stage_pass = [&](int buf, size_t aOff, size_t bOff) {
    #pragma unroll
    for (int i = 0; i < 4; ++i) {
      int row = i * 64 + srow;
      load_lds16(Abase + (size_t)row * (KA * 2) + aOff + scol,
                 (char*)&Als[buf][0] + (i * 512 + tid) * 16);
      load_lds16(Lbase + (size_t)row * 256 + bOff + scol,
                 (char*)&Bls[buf][0] + (i * 512 + tid) * 16);
    }
  };

  // swizzled read: bf16 idx = r*64 + ((chunk ^ (r&7)) * 8); r&7 == lr&7
  auto compute = [&](int buf) {
    #pragma unroll
    for (int kk = 0; kk < 2; ++kk) {
      short8_t wf[4];
      #pragma unroll
      for (int ni = 0; ni < 4; ++ni) {
        int r = wn * 64 + ni * 16 + lr;
        wf[ni] = *(const short8_t*)&Bls[buf][r * 64 + (((kk * 4 + lg) ^ (lr & 7)) * 8)];
      }
      #pragma unroll
      for (int g = 0; g < 2; ++g) {
        short8_t af[4];
        #pragma unroll
        for (int mi = 0; mi < 4; ++mi) {
          int r = wm * 128 + (g * 4 + mi) * 16 + lr;
          af[mi] = *(const short8_t*)&Als[buf][r * 64 + (((kk * 4 + lg) ^ (lr & 7)) * 8)];
        }
        __builtin_amdgcn_s_setprio(1);
        #pragma unroll
        for (int mi = 0; mi < 4; ++mi)
          #pragma unroll
          for (int ni = 0; ni < 4; ++ni)
            acc[g * 4 + mi][ni] = __builtin_amdgcn_mfma_f32_16x16x32_bf16(
                af[mi], wf[ni], acc[g * 4 + mi][ni], 0, 0, 0);
        __builtin_amdgcn_s_setprio(0);
      }
    }
  };

  // ---- prologue: tile 0 in flight ----
  stage_main(0);

  // ---- main K loop: 29 tiles, 2-buf, counted vmcnt (1-tile slack) ----
  int cur = 0;
  for (int t = 0; t < 29; ++t) {
    if (t < 28) stage_main(cur ^ 1);            // tile t+1 -> other buf
    __builtin_amdgcn_sched_barrier(0);
    if (t < 28) asm volatile("s_waitcnt vmcnt(8)" ::: "memory");  // tile t landed
    else        asm volatile("s_waitcnt vmcnt(0)" ::: "memory");
    __builtin_amdgcn_sched_barrier(0);
    __builtin_amdgcn_s_barrier();               // all waves: tile t staged
    __builtin_amdgcn_sched_barrier(0);
    compute(cur);
    __builtin_amdgcn_sched_barrier(0);
    __builtin_amdgcn_s_barrier();               // reads done before overwrite
    __builtin_amdgcn_sched_barrier(0);
    cur ^= 1;
  }

  // ---- issue loop-pass stages; theta log_cosh hides their latency ----
  stage_pass(0, (size_t)1728 * 2, 0);    // cv1 block x loop0 weights
  stage_pass(1, (size_t)1792 * 2, 128);  // cv2 block x loop1 weights

  // theta epilogue
  {
    #pragma unroll
    for (int mi = 0; mi < 8; ++mi)
      #pragma unroll
      for (int i = 0; i < 4; ++i) {
        float s = 0.f;
        #pragma unroll
        for (int ni = 0; ni < 4; ++ni) s += log_cosh_f(acc[mi][ni][i] + hidden_bias[lr]);
        rs[mi][i] += s;
      }
  }
  __syncthreads();  // full drain: loop-pass tiles staged & visible

  // loop-correlator passes (disjoint bufs, no LDS writes -> no barrier)
  #pragma unroll
  for (int pass = 0; pass < 2; ++pass) {
    #pragma unroll
    for (int i = 0; i < 8; ++i)
      #pragma unroll
      for (int jj = 0; jj < 4; ++jj)
        #pragma unroll
        for (int q = 0; q < 4; ++q) acc[i][jj][q] = 0.f;

    compute(pass);

    const float* lb = (pass == 0 ? l0hb : l1hb);
    #pragma unroll
    for (int mi = 0; mi < 8; ++mi)
      #pragma unroll
      for (int i = 0; i < 4; ++i) {
        float s = 0.f;
        #pragma unroll
        for (int ni = 0; ni < 4; ++ni) s += log_cosh_f(acc[mi][ni][i] + lb[lr]);
        rs[mi][i] += s;
      }
  }

  // reduce across the 16 lanes sharing each row, then atomicAdd
  #pragma unroll
  for (int mi = 0; mi < 8; ++mi)
    #pragma unroll
    for (int i = 0; i < 4; ++i) {
      float v = rs[mi][i];
      v += __shfl_xor(v, 1, 64);
      v += __shfl_xor(v, 2, 64);
      v += __shfl_xor(v, 4, 64);
      v += __shfl_xor(v, 8, 64);
      if (lr == 0) atomicAdd(&out[m0 + wm * 128 + mi * 16 + lg * 4 + i], v);
    }
}

// ============================================================
extern "C" void kernel_launch(void* const* d_in, const int* in_sizes, int n_in,
                              void* d_out, int out_size, void* d_ws, size_t ws_size,
                              hipStream_t stream) {
  const float* x            = (const float*)d_in[0];
  const float* hidden_bias  = (const float*)d_in[1];
  const float* symm_kernel  = (const float*)d_in[2];
  const float* visible_bias = (const float*)d_in[3];
  const float* corr0_bias   = (const float*)d_in[4];
  const float* corr0_kernel = (const float*)d_in[5];
  const float* corr1_bias   = (const float*)d_in[6];
  const float* corr1_kernel = (const float*)d_in[7];
  const float* corr2_bias   = (const float*)d_in[8];
  const float* corr2_kernel = (const float*)d_in[9];
  const float* l0hb         = (const float*)d_in[10];
  const float* l0k          = (const float*)d_in[11];
  const float* l1hb         = (const float*)d_in[12];
  const float* l1k          = (const float*)d_in[13];
  const int* symmetries     = (const int*)d_in[14];
  const int* idx0           = (const int*)d_in[15];
  const int* c0s            = (const int*)d_in[16];
  const int* idx1           = (const int*)d_in[17];
  const int* c1s            = (const int*)d_in[18];
  const int* idx2           = (const int*)d_in[19];
  const int* c2s            = (const int*)d_in[20];

  // workspace layout
  short* A   = (short*)d_ws;                                  // 30,408,704 B
  short* Wt  = (short*)((char*)d_ws + 30408704);              // 34,209,792 B
  short* Wlt = (short*)((char*)d_ws + 64618496);              //  2,359,296 B
  float* out = (float*)d_out;

  build_a_kernel<<<B_, 256, 0, stream>>>(x, visible_bias, corr0_bias, corr1_bias,
                                         corr2_bias, idx0, idx1, idx2, A, out);
  build_w_kernel<<<(NCOL * (KV / 8)) / 256, 256, 0, stream>>>(
      symm_kernel, symmetries, corr0_kernel, c0s, corr1_kernel, c1s,
      corr2_kernel, c2s, l0k, l1k, Wt, Wlt);
  gemm_fused<<<(B_ / 256) * (NCOL / 256), 512, 0, stream>>>(
      A, Wt, Wlt, hidden_bias, l0hb, l1hb, out);
}

// Round 11
// 821.129 us; speedup vs baseline: 1.2815x; 1.2815x over previous
//
#include <hip/hip_runtime.h>
#include <hip/hip_bf16.h>

// Problem constants
#define B_   8192
#define S_   1152
#define G_   576
#define F_   16
#define L_   24
#define NP_  576
#define KA   1856      // padded K of A / Wt (29 * 64)
#define NCOL 9216      // F*G
#define KV   1984      // KA + 128 (virtual K incl. loop-weight blocks)

typedef float f32x4 __attribute__((ext_vector_type(4)));
typedef short short8_t __attribute__((ext_vector_type(8)));

// ---- bf16 helpers (RNE) ----
__device__ __forceinline__ short f2bf(float v) {
  unsigned u = __float_as_uint(v);
  unsigned r = (u + 0x7fffu + ((u >> 16) & 1u)) >> 16;
  return (short)r;
}
__device__ __forceinline__ float bf2f(short s) {
  return __uint_as_float(((unsigned)(unsigned short)s) << 16);
}

__device__ __forceinline__ float log_cosh_f(float t) {
  float a = fabsf(t);
  return a + __logf(1.f + __expf(-2.f * a)) - 0.6931471805599453f;
}

__device__ __forceinline__ float wave_sum(float v) {
  #pragma unroll
  for (int d = 1; d < 64; d <<= 1) v += __shfl_xor(v, d, 64);
  return v;
}

__device__ __forceinline__ void load_lds16(const void* g, void* l) {
  __builtin_amdgcn_global_load_lds(
      (const __attribute__((address_space(1))) void*)g,
      (__attribute__((address_space(3))) void*)l, 16, 0, 0);
}

// ============================================================
// Kernel 1: build A (bf16 features) + bias -> out[b]
// ============================================================
__global__ __launch_bounds__(256) void build_a_kernel(
    const float* __restrict__ x, const float* __restrict__ vb,
    const float* __restrict__ cb0, const float* __restrict__ cb1,
    const float* __restrict__ cb2,
    const int* __restrict__ idx0, const int* __restrict__ idx1,
    const int* __restrict__ idx2,
    short* __restrict__ A, float* __restrict__ out) {
  int b = blockIdx.x, t = threadIdx.x;
  __shared__ float xs[S_];
  __shared__ float red[20];
  float se = 0.f, so = 0.f, s0 = 0.f, s1 = 0.f, s2 = 0.f;
  const float* xr = x + (size_t)b * S_;
  short* Ar = A + (size_t)b * KA;

  for (int i = t; i < S_; i += 256) {
    float v = xr[i];
    xs[i] = v;
    Ar[i] = f2bf(v);
    if (i & 1) so += v; else se += v;
  }
  __syncthreads();

  for (int c = t; c < NP_; c += 256) {
    const int* q = idx0 + c * 4;
    float p = xs[q[0]] * xs[q[1]] * xs[q[2]] * xs[q[3]];
    s0 += p;
    Ar[S_ + c] = f2bf(p);
  }
  if (t < L_) {
    const int* q = idx1 + t * L_;
    float p = 1.f;
    #pragma unroll
    for (int j = 0; j < L_; ++j) p *= xs[q[j]];
    s1 = p;
    short hi = f2bf(p);
    Ar[1728 + t] = hi;
    Ar[1752 + t] = f2bf(p - bf2f(hi));
  }
  if (t >= 32 && t < 32 + L_) {
    int l = t - 32;
    const int* q = idx2 + l * L_;
    float p = 1.f;
    #pragma unroll
    for (int j = 0; j < L_; ++j) p *= xs[q[j]];
    s2 = p;
    short hi = f2bf(p);
    Ar[1792 + l] = hi;
    Ar[1816 + l] = f2bf(p - bf2f(hi));
  }
  if (t >= 64 && t < 80) Ar[1776 + (t - 64)] = 0;
  if (t >= 80 && t < 96) Ar[1840 + (t - 80)] = 0;

  se = wave_sum(se); so = wave_sum(so);
  s0 = wave_sum(s0); s1 = wave_sum(s1); s2 = wave_sum(s2);
  int w = t >> 6;
  if ((t & 63) == 0) {
    red[w] = se; red[4 + w] = so; red[8 + w] = s0;
    red[12 + w] = s1; red[16 + w] = s2;
  }
  __syncthreads();
  if (t == 0) {
    float a  = red[0] + red[1] + red[2] + red[3];
    float bb = red[4] + red[5] + red[6] + red[7];
    float c0 = red[8] + red[9] + red[10] + red[11];
    float c1 = red[12] + red[13] + red[14] + red[15];
    float c2 = red[16] + red[17] + red[18] + red[19];
    out[b] = vb[0] * a + vb[1] * bb + cb0[0] * c0 + cb1[0] * c1 + cb2[0] * c2;
  }
}

// ============================================================
// Kernel 2: gather weights.
// ============================================================
__global__ __launch_bounds__(256) void build_w_kernel(
    const float* __restrict__ symm_kernel, const int* __restrict__ symmetries,
    const float* __restrict__ c0k, const int* __restrict__ c0s,
    const float* __restrict__ c1k, const int* __restrict__ c1s,
    const float* __restrict__ c2k, const int* __restrict__ c2s,
    const float* __restrict__ l0k, const float* __restrict__ l1k,
    short* __restrict__ Wt, short* __restrict__ Wlt) {
  const int CHUNKS = KV / 8;  // 248
  int t = blockIdx.x * 256 + threadIdx.x;
  int n = t / CHUNKS;
  if (n >= NCOL) return;
  int ch = t - n * CHUNKS;
  int g = n >> 4, f = n & 15;
  int k0 = ch * 8;
  short8_t pack;
  #pragma unroll
  for (int j = 0; j < 8; ++j) {
    int k = k0 + j;
    float val;
    if (k < 1152) {
      val = symm_kernel[f * S_ + symmetries[g * S_ + k]];
    } else if (k < 1728) {
      int c = k - 1152;
      val = c0k[f * NP_ + c0s[g * NP_ + c]];
    } else if (k < 1792) {
      int c = k - 1728;
      val = (c < 48) ? c1k[f * L_ + c1s[g * L_ + (c < 24 ? c : c - 24)]] : 0.f;
    } else if (k < 1856) {
      int c = k - 1792;
      val = (c < 48) ? c2k[f * L_ + c2s[g * L_ + (c < 24 ? c : c - 24)]] : 0.f;
    } else if (k < 1920) {
      int c = k - 1856;
      val = (c < 48) ? l0k[f * L_ + c1s[g * L_ + (c < 24 ? c : c - 24)]] : 0.f;
    } else {
      int c = k - 1920;
      val = (c < 48) ? l1k[f * L_ + c2s[g * L_ + (c < 24 ? c : c - 24)]] : 0.f;
    }
    pack[j] = f2bf(val);
  }
  if (k0 < KA) *(short8_t*)(Wt + (size_t)n * KA + k0) = pack;
  else         *(short8_t*)(Wlt + (size_t)n * 128 + (k0 - KA)) = pack;
}

// ============================================================
// Kernel 3: fused GEMM + log_cosh reduction.
// r10 post-mortem: 512-thr blocks ALWAYS clamp to 128 VGPR in this
// toolchain (r8 plain, r10 waves_per_eu(2,2)) -> 256^2 dead. Safe
// envelope: 256 thr + plain launch_bounds(256) -> 252 VGPR (r4).
// Consolidated theory: staged bytes / time == 5.2-5.6 TB/s in every
// clean run (L3-path wall; HBM FETCH only ~0.4 GB of 4.3 GB staged).
// Lever = staged bytes x L2-hit fraction.
// This round: 128x256 tile, 256 thr / 4 waves (2x2; wave = 64x128,
// acc[4][8] = 128 VGPR, rs init deferred to epilogue for liveness).
//  - staged bytes 4.53 -> 3.27 GB (-28%)
//  - r7-proven 3-buf 2-ahead counted-vmcnt pipeline; 12 loads/stage
//    -> steady vmcnt(24), tail 12 -> 0; LDS 144 KB; in-flight 96 KB
//  - XCD map: XCD owns 8 m-tiles, n walks slowest -> per-step panel
//    working set ~256 KB/XCD, ~16-step L2 skew tolerance
//  - XOR chunk swizzle (0 conflicts, r2-verified)
// ============================================================
__global__ __launch_bounds__(256)
void gemm_fused(
    const short* __restrict__ A, const short* __restrict__ Wt,
    const short* __restrict__ Wlt,
    const float* __restrict__ hidden_bias, const float* __restrict__ l0hb,
    const float* __restrict__ l1hb, float* __restrict__ out) {
  __shared__ short Als[3][128 * 64];
  __shared__ short Bls[3][256 * 64];
  const int tid = threadIdx.x;
  const int w = tid >> 6, lane = tid & 63;
  const int wm = w >> 1, wn = w & 1;          // wave = 64 rows x 128 cols
  const int lr = lane & 15, lg = lane >> 4;

  // XCD-aware tile mapping (bijective: 64 m-tiles = 8 XCD x 8; 36 n-tiles)
  const int bid = blockIdx.x;
  const int xcd = bid & 7;
  const int j   = bid >> 3;                   // 0..287
  const int mt  = (xcd << 3) | (j & 7);       // XCD owns 8 m-tiles
  const int nt  = j >> 3;                     // 0..35, n walks slowest
  const int m0 = mt * 128, n0 = nt * 256;

  // staging geometry: chunk p = i*256 + tid -> row = i*32 + (tid>>3)
  const int srow = tid >> 3;
  const int scol = ((tid & 7) ^ (srow & 7)) * 16;  // pre-swizzled src byte off

  f32x4 acc[4][8];
  #pragma unroll
  for (int i = 0; i < 4; ++i)
    #pragma unroll
    for (int jj = 0; jj < 8; ++jj)
      #pragma unroll
      for (int q = 0; q < 4; ++q) acc[i][jj][q] = 0.f;

  const char* Abase = (const char*)A + (size_t)m0 * (KA * 2);
  const char* Wbase = (const char*)Wt + (size_t)n0 * (KA * 2);
  const char* Lbase = (const char*)Wlt + (size_t)n0 * 256;

  // per-thread staging pointers, advanced +128 B per K-tile
  const char* pA[4];
  const char* pB[8];
  #pragma unroll
  for (int i = 0; i < 4; ++i)
    pA[i] = Abase + (size_t)(i * 32 + srow) * (KA * 2) + scol;
  #pragma unroll
  for (int i = 0; i < 8; ++i)
    pB[i] = Wbase + (size_t)(i * 32 + srow) * (KA * 2) + scol;

  auto stage_main = [&](int buf) {
    #pragma unroll
    for (int i = 0; i < 4; ++i) {
      load_lds16(pA[i], (char*)&Als[buf][0] + (i * 256 + tid) * 16);
      pA[i] += 128;
    }
    #pragma unroll
    for (int i = 0; i < 8; ++i) {
      load_lds16(pB[i], (char*)&Bls[buf][0] + (i * 256 + tid) * 16);
      pB[i] += 128;
    }
  };

  // loop-pass staging: A cv-block cols at aOff; Wlt rows (256 B stride)
  auto stage_pass = [&](int buf, size_t aOff, size_t bOff) {
    #pragma unroll
    for (int i = 0; i < 4; ++i) {
      int row = i * 32 + srow;
      load_lds16(Abase + (size_t)row * (KA * 2) + aOff + scol,
                 (char*)&Als[buf][0] + (i * 256 + tid) * 16);
    }
    #pragma unroll
    for (int i = 0; i < 8; ++i) {
      int row = i * 32 + srow;
      load_lds16(Lbase + (size_t)row * 256 + bOff + scol,
                 (char*)&Bls[buf][0] + (i * 256 + tid) * 16);
    }
  };

  // swizzled read: bf16 idx = r*64 + ((chunk ^ (r&7)) * 8); r&7 == lr&7
  auto compute = [&](int buf) {
    #pragma unroll
    for (int kk = 0; kk < 2; ++kk) {
      const int co = (((kk * 4 + lg) ^ (lr & 7)) * 8);
      short8_t af[4], wf[8];
      #pragma unroll
      for (int mi = 0; mi < 4; ++mi) {
        int r = wm * 64 + mi * 16 + lr;
        af[mi] = *(const short8_t*)&Als[buf][r * 64 + co];
      }
      #pragma unroll
      for (int ni = 0; ni < 8; ++ni) {
        int r = wn * 128 + ni * 16 + lr;
        wf[ni] = *(const short8_t*)&Bls[buf][r * 64 + co];
      }
      #pragma unroll
      for (int mi = 0; mi < 4; ++mi)
        #pragma unroll
        for (int ni = 0; ni < 8; ++ni)
          acc[mi][ni] = __builtin_amdgcn_mfma_f32_16x16x32_bf16(
              af[mi], wf[ni], acc[mi][ni], 0, 0, 0);
    }
  };

  // ---- prologue: 2 tiles in flight ----
  stage_main(0);
  stage_main(1);

  // ---- async main K loop: 29 tiles, 3-buf, counted vmcnt ----
  int bc = 0;  // compute buffer = t % 3
  for (int t = 0; t < 29; ++t) {
    if (t + 2 <= 28) {
      int bs = bc + 2; if (bs >= 3) bs -= 3;
      stage_main(bs);
    }
    __builtin_amdgcn_sched_barrier(0);
    if (t < 27)       asm volatile("s_waitcnt vmcnt(24)" ::: "memory");
    else if (t == 27) asm volatile("s_waitcnt vmcnt(12)" ::: "memory");
    else              asm volatile("s_waitcnt vmcnt(0)" ::: "memory");
    __builtin_amdgcn_sched_barrier(0);
    __builtin_amdgcn_s_barrier();                 // tile t staged for all
    __builtin_amdgcn_sched_barrier(0);
    compute(bc);
    __builtin_amdgcn_sched_barrier(0);
    __builtin_amdgcn_s_barrier();                 // reads done before overwrite
    __builtin_amdgcn_sched_barrier(0);
    bc = bc + 1; if (bc >= 3) bc = 0;
  }

  // ---- issue loop-pass stages; theta log_cosh hides their latency ----
  stage_pass(0, (size_t)1728 * 2, 0);    // cv1 block x loop0 weights
  stage_pass(1, (size_t)1792 * 2, 128);  // cv2 block x loop1 weights

  // rs lives only from here (keeps main-loop reg pressure down)
  float rs[4][4];
  {
    #pragma unroll
    for (int mi = 0; mi < 4; ++mi)
      #pragma unroll
      for (int i = 0; i < 4; ++i) {
        float s = 0.f;
        #pragma unroll
        for (int ni = 0; ni < 8; ++ni) s += log_cosh_f(acc[mi][ni][i] + hidden_bias[lr]);
        rs[mi][i] = s;
      }
  }
  __syncthreads();  // full drain: loop-pass tiles staged & visible

  // loop-correlator passes (disjoint bufs, no LDS writes -> no barrier)
  #pragma unroll
  for (int pass = 0; pass < 2; ++pass) {
    #pragma unroll
    for (int i = 0; i < 4; ++i)
      #pragma unroll
      for (int jj = 0; jj < 8; ++jj)
        #pragma unroll
        for (int q = 0; q < 4; ++q) acc[i][jj][q] = 0.f;

    compute(pass);

    const float* lb = (pass == 0 ? l0hb : l1hb);
    #pragma unroll
    for (int mi = 0; mi < 4; ++mi)
      #pragma unroll
      for (int i = 0; i < 4; ++i) {
        float s = 0.f;
        #pragma unroll
        for (int ni = 0; ni < 8; ++ni) s += log_cosh_f(acc[mi][ni][i] + lb[lr]);
        rs[mi][i] += s;
      }
  }

  // reduce across the 16 lanes sharing each row, then atomicAdd
  #pragma unroll
  for (int mi = 0; mi < 4; ++mi)
    #pragma unroll
    for (int i = 0; i < 4; ++i) {
      float v = rs[mi][i];
      v += __shfl_xor(v, 1, 64);
      v += __shfl_xor(v, 2, 64);
      v += __shfl_xor(v, 4, 64);
      v += __shfl_xor(v, 8, 64);
      if (lr == 0) atomicAdd(&out[m0 + wm * 64 + mi * 16 + lg * 4 + i], v);
    }
}

// ============================================================
extern "C" void kernel_launch(void* const* d_in, const int* in_sizes, int n_in,
                              void* d_out, int out_size, void* d_ws, size_t ws_size,
                              hipStream_t stream) {
  const float* x            = (const float*)d_in[0];
  const float* hidden_bias  = (const float*)d_in[1];
  const float* symm_kernel  = (const float*)d_in[2];
  const float* visible_bias = (const float*)d_in[3];
  const float* corr0_bias   = (const float*)d_in[4];
  const float* corr0_kernel = (const float*)d_in[5];
  const float* corr1_bias   = (const float*)d_in[6];
  const float* corr1_kernel = (const float*)d_in[7];
  const float* corr2_bias   = (const float*)d_in[8];
  const float* corr2_kernel = (const float*)d_in[9];
  const float* l0hb         = (const float*)d_in[10];
  const float* l0k          = (const float*)d_in[11];
  const float* l1hb         = (const float*)d_in[12];
  const float* l1k          = (const float*)d_in[13];
  const int* symmetries     = (const int*)d_in[14];
  const int* idx0           = (const int*)d_in[15];
  const int* c0s            = (const int*)d_in[16];
  const int* idx1           = (const int*)d_in[17];
  const int* c1s            = (const int*)d_in[18];
  const int* idx2           = (const int*)d_in[19];
  const int* c2s            = (const int*)d_in[20];

  // workspace layout
  short* A   = (short*)d_ws;                                  // 30,408,704 B
  short* Wt  = (short*)((char*)d_ws + 30408704);              // 34,209,792 B
  short* Wlt = (short*)((char*)d_ws + 64618496);              //  2,359,296 B
  float* out = (float*)d_out;

  build_a_kernel<<<B_, 256, 0, stream>>>(x, visible_bias, corr0_bias, corr1_bias,
                                         corr2_bias, idx0, idx1, idx2, A, out);
  build_w_kernel<<<(NCOL * (KV / 8)) / 256, 256, 0, stream>>>(
      symm_kernel, symmetries, corr0_kernel, c0s, corr1_kernel, c1s,
      corr2_kernel, c2s, l0k, l1k, Wt, Wlt);
  gemm_fused<<<(B_ / 128) * (NCOL / 256), 256, 0, stream>>>(
      A, Wt, Wlt, hidden_bias, l0hb, l1hb, out);
}

// Round 12
// 820.172 us; speedup vs baseline: 1.2830x; 1.0012x over previous
//
#include <hip/hip_runtime.h>
#include <hip/hip_bf16.h>

// Problem constants
#define B_   8192
#define S_   1152
#define G_   576
#define F_   16
#define L_   24
#define NP_  576
#define KA   1856      // padded K of A / Wt (29 * 64)
#define NCOL 9216      // F*G
#define KV   1984      // KA + 128 (virtual K incl. loop-weight blocks)

typedef float f32x4 __attribute__((ext_vector_type(4)));
typedef short short8_t __attribute__((ext_vector_type(8)));

// ---- bf16 helpers (RNE) ----
__device__ __forceinline__ short f2bf(float v) {
  unsigned u = __float_as_uint(v);
  unsigned r = (u + 0x7fffu + ((u >> 16) & 1u)) >> 16;
  return (short)r;
}
__device__ __forceinline__ float bf2f(short s) {
  return __uint_as_float(((unsigned)(unsigned short)s) << 16);
}

__device__ __forceinline__ float log_cosh_f(float t) {
  float a = fabsf(t);
  return a + __logf(1.f + __expf(-2.f * a)) - 0.6931471805599453f;
}

__device__ __forceinline__ float wave_sum(float v) {
  #pragma unroll
  for (int d = 1; d < 64; d <<= 1) v += __shfl_xor(v, d, 64);
  return v;
}

__device__ __forceinline__ void load_lds16(const void* g, void* l) {
  __builtin_amdgcn_global_load_lds(
      (const __attribute__((address_space(1))) void*)g,
      (__attribute__((address_space(3))) void*)l, 16, 0, 0);
}

// ============================================================
// Kernel 1: build A (bf16 features) + bias -> out[b]
// ============================================================
__global__ __launch_bounds__(256) void build_a_kernel(
    const float* __restrict__ x, const float* __restrict__ vb,
    const float* __restrict__ cb0, const float* __restrict__ cb1,
    const float* __restrict__ cb2,
    const int* __restrict__ idx0, const int* __restrict__ idx1,
    const int* __restrict__ idx2,
    short* __restrict__ A, float* __restrict__ out) {
  int b = blockIdx.x, t = threadIdx.x;
  __shared__ float xs[S_];
  __shared__ float red[20];
  float se = 0.f, so = 0.f, s0 = 0.f, s1 = 0.f, s2 = 0.f;
  const float* xr = x + (size_t)b * S_;
  short* Ar = A + (size_t)b * KA;

  for (int i = t; i < S_; i += 256) {
    float v = xr[i];
    xs[i] = v;
    Ar[i] = f2bf(v);
    if (i & 1) so += v; else se += v;
  }
  __syncthreads();

  for (int c = t; c < NP_; c += 256) {
    const int* q = idx0 + c * 4;
    float p = xs[q[0]] * xs[q[1]] * xs[q[2]] * xs[q[3]];
    s0 += p;
    Ar[S_ + c] = f2bf(p);
  }
  if (t < L_) {
    const int* q = idx1 + t * L_;
    float p = 1.f;
    #pragma unroll
    for (int j = 0; j < L_; ++j) p *= xs[q[j]];
    s1 = p;
    short hi = f2bf(p);
    Ar[1728 + t] = hi;
    Ar[1752 + t] = f2bf(p - bf2f(hi));
  }
  if (t >= 32 && t < 32 + L_) {
    int l = t - 32;
    const int* q = idx2 + l * L_;
    float p = 1.f;
    #pragma unroll
    for (int j = 0; j < L_; ++j) p *= xs[q[j]];
    s2 = p;
    short hi = f2bf(p);
    Ar[1792 + l] = hi;
    Ar[1816 + l] = f2bf(p - bf2f(hi));
  }
  if (t >= 64 && t < 80) Ar[1776 + (t - 64)] = 0;
  if (t >= 80 && t < 96) Ar[1840 + (t - 80)] = 0;

  se = wave_sum(se); so = wave_sum(so);
  s0 = wave_sum(s0); s1 = wave_sum(s1); s2 = wave_sum(s2);
  int w = t >> 6;
  if ((t & 63) == 0) {
    red[w] = se; red[4 + w] = so; red[8 + w] = s0;
    red[12 + w] = s1; red[16 + w] = s2;
  }
  __syncthreads();
  if (t == 0) {
    float a  = red[0] + red[1] + red[2] + red[3];
    float bb = red[4] + red[5] + red[6] + red[7];
    float c0 = red[8] + red[9] + red[10] + red[11];
    float c1 = red[12] + red[13] + red[14] + red[15];
    float c2 = red[16] + red[17] + red[18] + red[19];
    out[b] = vb[0] * a + vb[1] * bb + cb0[0] * c0 + cb1[0] * c1 + cb2[0] * c2;
  }
}

// ============================================================
// Kernel 2: gather weights.
// ============================================================
__global__ __launch_bounds__(256) void build_w_kernel(
    const float* __restrict__ symm_kernel, const int* __restrict__ symmetries,
    const float* __restrict__ c0k, const int* __restrict__ c0s,
    const float* __restrict__ c1k, const int* __restrict__ c1s,
    const float* __restrict__ c2k, const int* __restrict__ c2s,
    const float* __restrict__ l0k, const float* __restrict__ l1k,
    short* __restrict__ Wt, short* __restrict__ Wlt) {
  const int CHUNKS = KV / 8;  // 248
  int t = blockIdx.x * 256 + threadIdx.x;
  int n = t / CHUNKS;
  if (n >= NCOL) return;
  int ch = t - n * CHUNKS;
  int g = n >> 4, f = n & 15;
  int k0 = ch * 8;
  short8_t pack;
  #pragma unroll
  for (int j = 0; j < 8; ++j) {
    int k = k0 + j;
    float val;
    if (k < 1152) {
      val = symm_kernel[f * S_ + symmetries[g * S_ + k]];
    } else if (k < 1728) {
      int c = k - 1152;
      val = c0k[f * NP_ + c0s[g * NP_ + c]];
    } else if (k < 1792) {
      int c = k - 1728;
      val = (c < 48) ? c1k[f * L_ + c1s[g * L_ + (c < 24 ? c : c - 24)]] : 0.f;
    } else if (k < 1856) {
      int c = k - 1792;
      val = (c < 48) ? c2k[f * L_ + c2s[g * L_ + (c < 24 ? c : c - 24)]] : 0.f;
    } else if (k < 1920) {
      int c = k - 1856;
      val = (c < 48) ? l0k[f * L_ + c1s[g * L_ + (c < 24 ? c : c - 24)]] : 0.f;
    } else {
      int c = k - 1920;
      val = (c < 48) ? l1k[f * L_ + c2s[g * L_ + (c < 24 ? c : c - 24)]] : 0.f;
    }
    pack[j] = f2bf(val);
  }
  if (k0 < KA) *(short8_t*)(Wt + (size_t)n * KA + k0) = pack;
  else         *(short8_t*)(Wlt + (size_t)n * 128 + (k0 - KA)) = pack;
}

// ============================================================
// Kernel 3: fused GEMM + log_cosh reduction.
// r11 post-mortem: two confirmed levers never yet combined:
//   (1) staged bytes (r11: -28% bytes -> -10% time)
//   (2) >=2 blocks/CU (everything at 1 block/CU stalls ~90%/step)
// 128x192 is the unique tile where both fit: 2-buf LDS = 80 KB
// -> EXACTLY 2 blocks/CU (160 KB), 8 waves/CU cross-block overlap;
// staged bytes 3.56 GB (~r11); acc[4][6]=96 VGPR -> ~190 demand,
// no spill in the 256-thr/252-VGPR envelope (r10 law: 512-thr dead).
//  - counted-vmcnt 2-buf async (r7/r11-proven): stage(t+1);
//    vmcnt(10); bar; compute(t); bar
//  - XCD map: resident 64 blocks/XCD = 8 mt x 8 nt -> each panel
//    serves 8 co-resident blocks from L2
//  - XOR chunk swizzle (0 conflicts, r2-verified)
// ============================================================
__global__ __launch_bounds__(256)
void gemm_fused(
    const short* __restrict__ A, const short* __restrict__ Wt,
    const short* __restrict__ Wlt,
    const float* __restrict__ hidden_bias, const float* __restrict__ l0hb,
    const float* __restrict__ l1hb, float* __restrict__ out) {
  __shared__ short Als[2][128 * 64];
  __shared__ short Bls[2][192 * 64];
  const int tid = threadIdx.x;
  const int w = tid >> 6, lane = tid & 63;
  const int wm = w >> 1, wn = w & 1;          // wave = 64 rows x 96 cols
  const int lr = lane & 15, lg = lane >> 4;

  // XCD-aware tile mapping (bijective: 8 xcd x 8 mt x 48 nt = 3072)
  const int bid = blockIdx.x;
  const int xcd = bid & 7;
  const int j   = bid >> 3;                   // 0..383
  const int mt  = (xcd << 3) | (j & 7);       // XCD owns 8 m-tiles
  const int nt  = j >> 3;                     // 0..47, n walks slowest
  const int m0 = mt * 128, n0 = nt * 192;

  // staging geometry: chunk p = i*256 + tid -> row = i*32 + (tid>>3)
  const int srow = tid >> 3;
  const int scol = ((tid & 7) ^ (srow & 7)) * 16;  // pre-swizzled src byte off

  f32x4 acc[4][6];
  #pragma unroll
  for (int i = 0; i < 4; ++i)
    #pragma unroll
    for (int jj = 0; jj < 6; ++jj)
      #pragma unroll
      for (int q = 0; q < 4; ++q) acc[i][jj][q] = 0.f;

  const char* Abase = (const char*)A + (size_t)m0 * (KA * 2);
  const char* Wbase = (const char*)Wt + (size_t)n0 * (KA * 2);
  const char* Lbase = (const char*)Wlt + (size_t)n0 * 256;

  // per-thread staging pointers, advanced +128 B per K-tile
  const char* pA[4];
  const char* pB[6];
  #pragma unroll
  for (int i = 0; i < 4; ++i)
    pA[i] = Abase + (size_t)(i * 32 + srow) * (KA * 2) + scol;
  #pragma unroll
  for (int i = 0; i < 6; ++i)
    pB[i] = Wbase + (size_t)(i * 32 + srow) * (KA * 2) + scol;

  auto stage_main = [&](int buf) {
    #pragma unroll
    for (int i = 0; i < 4; ++i) {
      load_lds16(pA[i], (char*)&Als[buf][0] + (i * 256 + tid) * 16);
      pA[i] += 128;
    }
    #pragma unroll
    for (int i = 0; i < 6; ++i) {
      load_lds16(pB[i], (char*)&Bls[buf][0] + (i * 256 + tid) * 16);
      pB[i] += 128;
    }
  };

  // loop-pass staging: A cv-block cols at aOff; Wlt rows (256 B stride)
  auto stage_pass = [&](int buf, size_t aOff, size_t bOff) {
    #pragma unroll
    for (int i = 0; i < 4; ++i) {
      int row = i * 32 + srow;
      load_lds16(Abase + (size_t)row * (KA * 2) + aOff + scol,
                 (char*)&Als[buf][0] + (i * 256 + tid) * 16);
    }
    #pragma unroll
    for (int i = 0; i < 6; ++i) {
      int row = i * 32 + srow;
      load_lds16(Lbase + (size_t)row * 256 + bOff + scol,
                 (char*)&Bls[buf][0] + (i * 256 + tid) * 16);
    }
  };

  // swizzled read: bf16 idx = r*64 + ((chunk ^ (r&7)) * 8); r&7 == lr&7
  auto compute = [&](int buf) {
    #pragma unroll
    for (int kk = 0; kk < 2; ++kk) {
      const int co = (((kk * 4 + lg) ^ (lr & 7)) * 8);
      short8_t af[4], wf[6];
      #pragma unroll
      for (int mi = 0; mi < 4; ++mi) {
        int r = wm * 64 + mi * 16 + lr;
        af[mi] = *(const short8_t*)&Als[buf][r * 64 + co];
      }
      #pragma unroll
      for (int ni = 0; ni < 6; ++ni) {
        int r = wn * 96 + ni * 16 + lr;
        wf[ni] = *(const short8_t*)&Bls[buf][r * 64 + co];
      }
      #pragma unroll
      for (int mi = 0; mi < 4; ++mi)
        #pragma unroll
        for (int ni = 0; ni < 6; ++ni)
          acc[mi][ni] = __builtin_amdgcn_mfma_f32_16x16x32_bf16(
              af[mi], wf[ni], acc[mi][ni], 0, 0, 0);
    }
  };

  // ---- prologue: tile 0 in flight ----
  stage_main(0);

  // ---- async main K loop: 29 tiles, 2-buf, counted vmcnt ----
  int cur = 0;
  for (int t = 0; t < 29; ++t) {
    if (t < 28) stage_main(cur ^ 1);            // tile t+1 -> other buf
    __builtin_amdgcn_sched_barrier(0);
    if (t < 28) asm volatile("s_waitcnt vmcnt(10)" ::: "memory");  // tile t landed
    else        asm volatile("s_waitcnt vmcnt(0)" ::: "memory");
    __builtin_amdgcn_sched_barrier(0);
    __builtin_amdgcn_s_barrier();               // all waves: tile t staged
    __builtin_amdgcn_sched_barrier(0);
    compute(cur);
    __builtin_amdgcn_sched_barrier(0);
    __builtin_amdgcn_s_barrier();               // reads done before overwrite
    __builtin_amdgcn_sched_barrier(0);
    cur ^= 1;
  }

  // ---- issue loop-pass stages; theta log_cosh hides their latency ----
  stage_pass(0, (size_t)1728 * 2, 0);    // cv1 block x loop0 weights
  stage_pass(1, (size_t)1792 * 2, 128);  // cv2 block x loop1 weights

  // rs lives only from here (keeps main-loop reg pressure down)
  float rs[4][4];
  {
    #pragma unroll
    for (int mi = 0; mi < 4; ++mi)
      #pragma unroll
      for (int i = 0; i < 4; ++i) {
        float s = 0.f;
        #pragma unroll
        for (int ni = 0; ni < 6; ++ni) s += log_cosh_f(acc[mi][ni][i] + hidden_bias[lr]);
        rs[mi][i] = s;
      }
  }
  __syncthreads();  // full drain: loop-pass tiles staged & visible

  // loop-correlator passes (disjoint bufs, no LDS writes -> no barrier)
  #pragma unroll
  for (int pass = 0; pass < 2; ++pass) {
    #pragma unroll
    for (int i = 0; i < 4; ++i)
      #pragma unroll
      for (int jj = 0; jj < 6; ++jj)
        #pragma unroll
        for (int q = 0; q < 4; ++q) acc[i][jj][q] = 0.f;

    compute(pass);

    const float* lb = (pass == 0 ? l0hb : l1hb);
    #pragma unroll
    for (int mi = 0; mi < 4; ++mi)
      #pragma unroll
      for (int i = 0; i < 4; ++i) {
        float s = 0.f;
        #pragma unroll
        for (int ni = 0; ni < 6; ++ni) s += log_cosh_f(acc[mi][ni][i] + lb[lr]);
        rs[mi][i] += s;
      }
  }

  // reduce across the 16 lanes sharing each row, then atomicAdd
  #pragma unroll
  for (int mi = 0; mi < 4; ++mi)
    #pragma unroll
    for (int i = 0; i < 4; ++i) {
      float v = rs[mi][i];
      v += __shfl_xor(v, 1, 64);
      v += __shfl_xor(v, 2, 64);
      v += __shfl_xor(v, 4, 64);
      v += __shfl_xor(v, 8, 64);
      if (lr == 0) atomicAdd(&out[m0 + wm * 64 + mi * 16 + lg * 4 + i], v);
    }
}

// ============================================================
extern "C" void kernel_launch(void* const* d_in, const int* in_sizes, int n_in,
                              void* d_out, int out_size, void* d_ws, size_t ws_size,
                              hipStream_t stream) {
  const float* x            = (const float*)d_in[0];
  const float* hidden_bias  = (const float*)d_in[1];
  const float* symm_kernel  = (const float*)d_in[2];
  const float* visible_bias = (const float*)d_in[3];
  const float* corr0_bias   = (const float*)d_in[4];
  const float* corr0_kernel = (const float*)d_in[5];
  const float* corr1_bias   = (const float*)d_in[6];
  const float* corr1_kernel = (const float*)d_in[7];
  const float* corr2_bias   = (const float*)d_in[8];
  const float* corr2_kernel = (const float*)d_in[9];
  const float* l0hb         = (const float*)d_in[10];
  const float* l0k          = (const float*)d_in[11];
  const float* l1hb         = (const float*)d_in[12];
  const float* l1k          = (const float*)d_in[13];
  const int* symmetries     = (const int*)d_in[14];
  const int* idx0           = (const int*)d_in[15];
  const int* c0s            = (const int*)d_in[16];
  const int* idx1           = (const int*)d_in[17];
  const int* c1s            = (const int*)d_in[18];
  const int* idx2           = (const int*)d_in[19];
  const int* c2s            = (const int*)d_in[20];

  // workspace layout
  short* A   = (short*)d_ws;                                  // 30,408,704 B
  short* Wt  = (short*)((char*)d_ws + 30408704);              // 34,209,792 B
  short* Wlt = (short*)((char*)d_ws + 64618496);              //  2,359,296 B
  float* out = (float*)d_out;

  build_a_kernel<<<B_, 256, 0, stream>>>(x, visible_bias, corr0_bias, corr1_bias,
                                         corr2_bias, idx0, idx1, idx2, A, out);
  build_w_kernel<<<(NCOL * (KV / 8)) / 256, 256, 0, stream>>>(
      symm_kernel, symmetries, corr0_kernel, c0s, corr1_kernel, c1s,
      corr2_kernel, c2s, l0k, l1k, Wt, Wlt);
  gemm_fused<<<(B_ / 128) * (NCOL / 192), 256, 0, stream>>>(
      A, Wt, Wlt, hidden_bias, l0hb, l1hb, out);
}

// Round 13
// 788.786 us; speedup vs baseline: 1.3340x; 1.0398x over previous
//
#include <hip/hip_runtime.h>
#include <hip/hip_bf16.h>

// Problem constants
#define B_   8192
#define S_   1152
#define G_   576
#define F_   16
#define L_   24
#define NP_  576
#define KA   1856      // padded K of A / Wt (29 * 64)
#define NCOL 9216      // F*G
#define KV   1984      // KA + 128 (virtual K incl. loop-weight blocks)

typedef float f32x4 __attribute__((ext_vector_type(4)));
typedef short short8_t __attribute__((ext_vector_type(8)));

// ---- bf16 helpers (RNE) ----
__device__ __forceinline__ short f2bf(float v) {
  unsigned u = __float_as_uint(v);
  unsigned r = (u + 0x7fffu + ((u >> 16) & 1u)) >> 16;
  return (short)r;
}
__device__ __forceinline__ float bf2f(short s) {
  return __uint_as_float(((unsigned)(unsigned short)s) << 16);
}

__device__ __forceinline__ float log_cosh_f(float t) {
  float a = fabsf(t);
  return a + __logf(1.f + __expf(-2.f * a)) - 0.6931471805599453f;
}

__device__ __forceinline__ float wave_sum(float v) {
  #pragma unroll
  for (int d = 1; d < 64; d <<= 1) v += __shfl_xor(v, d, 64);
  return v;
}

__device__ __forceinline__ void load_lds16(const void* g, void* l) {
  __builtin_amdgcn_global_load_lds(
      (const __attribute__((address_space(1))) void*)g,
      (__attribute__((address_space(3))) void*)l, 16, 0, 0);
}

// ============================================================
// Kernel 1: build A (bf16 features) + bias -> out[b]
// ============================================================
__global__ __launch_bounds__(256) void build_a_kernel(
    const float* __restrict__ x, const float* __restrict__ vb,
    const float* __restrict__ cb0, const float* __restrict__ cb1,
    const float* __restrict__ cb2,
    const int* __restrict__ idx0, const int* __restrict__ idx1,
    const int* __restrict__ idx2,
    short* __restrict__ A, float* __restrict__ out) {
  int b = blockIdx.x, t = threadIdx.x;
  __shared__ float xs[S_];
  __shared__ float red[20];
  float se = 0.f, so = 0.f, s0 = 0.f, s1 = 0.f, s2 = 0.f;
  const float* xr = x + (size_t)b * S_;
  short* Ar = A + (size_t)b * KA;

  for (int i = t; i < S_; i += 256) {
    float v = xr[i];
    xs[i] = v;
    Ar[i] = f2bf(v);
    if (i & 1) so += v; else se += v;
  }
  __syncthreads();

  for (int c = t; c < NP_; c += 256) {
    const int* q = idx0 + c * 4;
    float p = xs[q[0]] * xs[q[1]] * xs[q[2]] * xs[q[3]];
    s0 += p;
    Ar[S_ + c] = f2bf(p);
  }
  if (t < L_) {
    const int* q = idx1 + t * L_;
    float p = 1.f;
    #pragma unroll
    for (int j = 0; j < L_; ++j) p *= xs[q[j]];
    s1 = p;
    short hi = f2bf(p);
    Ar[1728 + t] = hi;
    Ar[1752 + t] = f2bf(p - bf2f(hi));
  }
  if (t >= 32 && t < 32 + L_) {
    int l = t - 32;
    const int* q = idx2 + l * L_;
    float p = 1.f;
    #pragma unroll
    for (int j = 0; j < L_; ++j) p *= xs[q[j]];
    s2 = p;
    short hi = f2bf(p);
    Ar[1792 + l] = hi;
    Ar[1816 + l] = f2bf(p - bf2f(hi));
  }
  if (t >= 64 && t < 80) Ar[1776 + (t - 64)] = 0;
  if (t >= 80 && t < 96) Ar[1840 + (t - 80)] = 0;

  se = wave_sum(se); so = wave_sum(so);
  s0 = wave_sum(s0); s1 = wave_sum(s1); s2 = wave_sum(s2);
  int w = t >> 6;
  if ((t & 63) == 0) {
    red[w] = se; red[4 + w] = so; red[8 + w] = s0;
    red[12 + w] = s1; red[16 + w] = s2;
  }
  __syncthreads();
  if (t == 0) {
    float a  = red[0] + red[1] + red[2] + red[3];
    float bb = red[4] + red[5] + red[6] + red[7];
    float c0 = red[8] + red[9] + red[10] + red[11];
    float c1 = red[12] + red[13] + red[14] + red[15];
    float c2 = red[16] + red[17] + red[18] + red[19];
    out[b] = vb[0] * a + vb[1] * bb + cb0[0] * c0 + cb1[0] * c1 + cb2[0] * c2;
  }
}

// ============================================================
// Kernel 2: gather weights.
// ============================================================
__global__ __launch_bounds__(256) void build_w_kernel(
    const float* __restrict__ symm_kernel, const int* __restrict__ symmetries,
    const float* __restrict__ c0k, const int* __restrict__ c0s,
    const float* __restrict__ c1k, const int* __restrict__ c1s,
    const float* __restrict__ c2k, const int* __restrict__ c2s,
    const float* __restrict__ l0k, const float* __restrict__ l1k,
    short* __restrict__ Wt, short* __restrict__ Wlt) {
  const int CHUNKS = KV / 8;  // 248
  int t = blockIdx.x * 256 + threadIdx.x;
  int n = t / CHUNKS;
  if (n >= NCOL) return;
  int ch = t - n * CHUNKS;
  int g = n >> 4, f = n & 15;
  int k0 = ch * 8;
  short8_t pack;
  #pragma unroll
  for (int j = 0; j < 8; ++j) {
    int k = k0 + j;
    float val;
    if (k < 1152) {
      val = symm_kernel[f * S_ + symmetries[g * S_ + k]];
    } else if (k < 1728) {
      int c = k - 1152;
      val = c0k[f * NP_ + c0s[g * NP_ + c]];
    } else if (k < 1792) {
      int c = k - 1728;
      val = (c < 48) ? c1k[f * L_ + c1s[g * L_ + (c < 24 ? c : c - 24)]] : 0.f;
    } else if (k < 1856) {
      int c = k - 1792;
      val = (c < 48) ? c2k[f * L_ + c2s[g * L_ + (c < 24 ? c : c - 24)]] : 0.f;
    } else if (k < 1920) {
      int c = k - 1856;
      val = (c < 48) ? l0k[f * L_ + c1s[g * L_ + (c < 24 ? c : c - 24)]] : 0.f;
    } else {
      int c = k - 1920;
      val = (c < 48) ? l1k[f * L_ + c2s[g * L_ + (c < 24 ? c : c - 24)]] : 0.f;
    }
    pack[j] = f2bf(val);
  }
  if (k0 < KA) *(short8_t*)(Wt + (size_t)n * KA + k0) = pack;
  else         *(short8_t*)(Wlt + (size_t)n * 128 + (k0 - KA)) = pack;
}

// ============================================================
// Kernel 3: fused GEMM + log_cosh reduction.
// r12 post-mortem: exact-fit 2-block configs never co-schedule
// (occ pinned ~12% = 1 block/CU). m97 reference = 13.4 TB/s staged
// at ~3 blocks/CU vs our 5.1-5.6 TB/s at 1 block -> co-residency is
// the whole game. r8/r10 law: 512-thr blocks clamp at 128 VGPR.
// This round: DESIGN INTO the clamp. 512 thr / 8 waves (4M x 2N),
// 128x128 tile, wave = 32x64 -> acc[2][4] = 32 VGPR, demand ~100
// << 128 -> no spill. Single 32 KB LDS buffer, plain m97 2-barrier
// loop (cross-BLOCK overlap is the hiding mechanism, m114).
// VGPR 128 -> 4 waves/SIMD; LDS 2x32=64 KB of 160 -> 2 blocks x 8
// waves = 16 waves/CU with wide margins on both resources.
//  - XOR chunk swizzle (0 conflicts, r2-verified)
//  - XCD supertile map (8 mt x 9 nt per XCD window)
//  - T14 epilogue: stage pass under theta log_cosh
// ============================================================
__global__ __launch_bounds__(512)
void gemm_fused(
    const short* __restrict__ A, const short* __restrict__ Wt,
    const short* __restrict__ Wlt,
    const float* __restrict__ hidden_bias, const float* __restrict__ l0hb,
    const float* __restrict__ l1hb, float* __restrict__ out) {
  __shared__ short Als[128 * 64];
  __shared__ short Bls[128 * 64];
  const int tid = threadIdx.x;
  const int w = tid >> 6, lane = tid & 63;
  const int wm = w >> 1, wn = w & 1;          // 4M x 2N waves; wave = 32 x 64
  const int lr = lane & 15, lg = lane >> 4;

  // XCD-aware tile mapping (bijective: 8 xcd x 8 mt x 72 nt = 4608)
  const int bid = blockIdx.x;
  const int xcd = bid & 7;
  const int idx = bid >> 3;         // 0..575
  const int st  = idx >> 6;         // supertile column 0..8
  const int u   = idx & 63;
  const int m0 = (xcd * 8 + (u & 7)) * 128;
  const int n0 = (st * 8 + (u >> 3)) * 128;

  // staging: chunk p = i*512 + tid -> row = i*64 + (tid>>3), slot = tid&7
  const int srow = tid >> 3;
  const int scol = ((tid & 7) ^ (srow & 7)) * 16;  // pre-swizzled src byte off

  f32x4 acc[2][4];
  float rs[2][4];
  #pragma unroll
  for (int i = 0; i < 2; ++i)
    #pragma unroll
    for (int j = 0; j < 4; ++j) {
      #pragma unroll
      for (int q = 0; q < 4; ++q) acc[i][j][q] = 0.f;
      rs[i][j] = 0.f;
    }

  const char* Abase = (const char*)A + (size_t)m0 * (KA * 2);
  const char* Wbase = (const char*)Wt + (size_t)n0 * (KA * 2);
  const char* Lbase = (const char*)Wlt + (size_t)n0 * 256;

  // stage one 128x64 A-tile + B-tile (2+2 chunks per thread)
  auto stage = [&](size_t aOff, const char* bSrc, size_t bStride, size_t bOff) {
    #pragma unroll
    for (int i = 0; i < 2; ++i) {
      int row = i * 64 + srow;
      load_lds16(Abase + (size_t)row * (KA * 2) + aOff + scol,
                 (char*)Als + (i * 512 + tid) * 16);
      load_lds16(bSrc + (size_t)row * bStride + bOff + scol,
                 (char*)Bls + (i * 512 + tid) * 16);
    }
  };

  // swizzled bf16 read idx: row*64 + ((chunk ^ (row&7)) * 8); row&7 == lr&7
  auto compute = [&]() {
    #pragma unroll
    for (int kk = 0; kk < 2; ++kk) {
      const int co = (((kk * 4 + lg) ^ (lr & 7)) * 8);
      short8_t af[2], wf[4];
      #pragma unroll
      for (int mi = 0; mi < 2; ++mi) {
        int row = wm * 32 + mi * 16 + lr;
        af[mi] = *(const short8_t*)&Als[row * 64 + co];
      }
      #pragma unroll
      for (int ni = 0; ni < 4; ++ni) {
        int row = wn * 64 + ni * 16 + lr;
        wf[ni] = *(const short8_t*)&Bls[row * 64 + co];
      }
      #pragma unroll
      for (int mi = 0; mi < 2; ++mi)
        #pragma unroll
        for (int ni = 0; ni < 4; ++ni)
          acc[mi][ni] = __builtin_amdgcn_mfma_f32_16x16x32_bf16(
              af[mi], wf[ni], acc[mi][ni], 0, 0, 0);
    }
  };

  auto lc_accum = [&](const float* bias) {
    #pragma unroll
    for (int mi = 0; mi < 2; ++mi)
      #pragma unroll
      for (int i = 0; i < 4; ++i) {
        float s = 0.f;
        #pragma unroll
        for (int ni = 0; ni < 4; ++ni) s += log_cosh_f(acc[mi][ni][i] + bias[lr]);
        rs[mi][i] += s;
      }
  };

  const size_t WS = (size_t)(KA * 2);

  // ---- main K loop: m97 2-barrier structure, 29 steps ----
  stage(0, Wbase, WS, 0);
  for (int t = 0; t < 29; ++t) {
    __syncthreads();            // drain (vmcnt0) + barrier: tile t visible
    compute();
    __syncthreads();            // all reads done before overwrite
    if (t < 28) stage((size_t)(t + 1) * 128, Wbase, WS, (size_t)(t + 1) * 128);
  }

  // ---- epilogue: T14 chain ----
  stage((size_t)1728 * 2, Lbase, 256, 0);     // pass0: cv1 x loop0
  lc_accum(hidden_bias);                      // theta log_cosh hides p0 stage
  __syncthreads();

  #pragma unroll
  for (int i = 0; i < 2; ++i)
    #pragma unroll
    for (int j = 0; j < 4; ++j)
      #pragma unroll
      for (int q = 0; q < 4; ++q) acc[i][j][q] = 0.f;
  compute();                                  // pass0 MFMA
  __syncthreads();
  stage((size_t)1792 * 2, Lbase, 256, 128);   // pass1: cv2 x loop1
  lc_accum(l0hb);                             // pass0 log_cosh hides p1 stage
  __syncthreads();

  #pragma unroll
  for (int i = 0; i < 2; ++i)
    #pragma unroll
    for (int j = 0; j < 4; ++j)
      #pragma unroll
      for (int q = 0; q < 4; ++q) acc[i][j][q] = 0.f;
  compute();                                  // pass1 MFMA
  lc_accum(l1hb);

  // reduce across the 16 lanes sharing each row, then atomicAdd
  #pragma unroll
  for (int mi = 0; mi < 2; ++mi)
    #pragma unroll
    for (int i = 0; i < 4; ++i) {
      float v = rs[mi][i];
      v += __shfl_xor(v, 1, 64);
      v += __shfl_xor(v, 2, 64);
      v += __shfl_xor(v, 4, 64);
      v += __shfl_xor(v, 8, 64);
      if (lr == 0) atomicAdd(&out[m0 + wm * 32 + mi * 16 + lg * 4 + i], v);
    }
}

// ============================================================
extern "C" void kernel_launch(void* const* d_in, const int* in_sizes, int n_in,
                              void* d_out, int out_size, void* d_ws, size_t ws_size,
                              hipStream_t stream) {
  const float* x            = (const float*)d_in[0];
  const float* hidden_bias  = (const float*)d_in[1];
  const float* symm_kernel  = (const float*)d_in[2];
  const float* visible_bias = (const float*)d_in[3];
  const float* corr0_bias   = (const float*)d_in[4];
  const float* corr0_kernel = (const float*)d_in[5];
  const float* corr1_bias   = (const float*)d_in[6];
  const float* corr1_kernel = (const float*)d_in[7];
  const float* corr2_bias   = (const float*)d_in[8];
  const float* corr2_kernel = (const float*)d_in[9];
  const float* l0hb         = (const float*)d_in[10];
  const float* l0k          = (const float*)d_in[11];
  const float* l1hb         = (const float*)d_in[12];
  const float* l1k          = (const float*)d_in[13];
  const int* symmetries     = (const int*)d_in[14];
  const int* idx0           = (const int*)d_in[15];
  const int* c0s            = (const int*)d_in[16];
  const int* idx1           = (const int*)d_in[17];
  const int* c1s            = (const int*)d_in[18];
  const int* idx2           = (const int*)d_in[19];
  const int* c2s            = (const int*)d_in[20];

  // workspace layout
  short* A   = (short*)d_ws;                                  // 30,408,704 B
  short* Wt  = (short*)((char*)d_ws + 30408704);              // 34,209,792 B
  short* Wlt = (short*)((char*)d_ws + 64618496);              //  2,359,296 B
  float* out = (float*)d_out;

  build_a_kernel<<<B_, 256, 0, stream>>>(x, visible_bias, corr0_bias, corr1_bias,
                                         corr2_bias, idx0, idx1, idx2, A, out);
  build_w_kernel<<<(NCOL * (KV / 8)) / 256, 256, 0, stream>>>(
      symm_kernel, symmetries, corr0_kernel, c0s, corr1_kernel, c1s,
      corr2_kernel, c2s, l0k, l1k, Wt, Wlt);
  gemm_fused<<<4608, 512, 0, stream>>>(
      A, Wt, Wlt, hidden_bias, l0hb, l1hb, out);
}